// Round 3
// baseline (194.479 us; speedup 1.0000x reference)
//
#include <hip/hip_runtime.h>
#include <hip/hip_bf16.h>
#include <math.h>

#define Bn 8
#define Ln 512
#define Dn 768
#define NHn 12
#define DHn 64
#define K1n 20
#define K2n 20
#define NGRP 4
#define HPG 3                 // heads per group
#define GSTRIDE 2097152       // floats per loc partial buffer (8*512*512)

// workspace layout (bytes)
#define WS_ACC    0           // double acc[8]: [0]=pair_num [1]=trip_num [2]=trip_cnt
#define WS_GSCORE 64          // float g_score[8*512]
#define WS_LOC    16448       // float loc_part[4][8*512*512] (32 MB)
#define WS_GTOP   33570880    // int g_top[8*20]
#define WS_LTOP   33571520    // int l_top[8*20*20]
#define WS_SBF    33584320    // ushort sbf[8*12*512*64] bf16 head-major
#define WS_TBF    39875776    // ushort tbf[...]  (ends 46167232)
#define WS_ZERO_BYTES 16448   // acc + g_score only

typedef __attribute__((ext_vector_type(8))) short bf16x8;
typedef __attribute__((ext_vector_type(4))) float f32x4;

__device__ inline unsigned short f2bf(float x) {
  __hip_bfloat16 h = __float2bfloat16(x);
  return *reinterpret_cast<unsigned short*>(&h);
}

// ---------------------------------------------------------------------------
// Prep: fp32 [b][row][h*64+k] -> bf16 head-major [b][h][row][k]
// ---------------------------------------------------------------------------
__global__ __launch_bounds__(256) void prep_bf16_kernel(
    const float* __restrict__ s, const float* __restrict__ t,
    unsigned short* __restrict__ sbf, unsigned short* __restrict__ tbf) {
  int gid = blockIdx.x * 256 + threadIdx.x;
  int f = gid * 4;
  int col = f % Dn;
  int rb = f / Dn;
  int row = rb & (Ln - 1);
  int b = rb >> 9;
  int h = col >> 6;
  int k = col & 63;
  size_t dst = (((size_t)(b * NHn + h) * Ln + row) * DHn + k);
  float4 vs = *(const float4*)(s + f);
  float4 vt = *(const float4*)(t + f);
  ushort4 us, ut;
  us.x = f2bf(vs.x); us.y = f2bf(vs.y); us.z = f2bf(vs.z); us.w = f2bf(vs.w);
  ut.x = f2bf(vt.x); ut.y = f2bf(vt.y); ut.z = f2bf(vt.z); ut.w = f2bf(vt.w);
  *(ushort4*)(sbf + dst) = us;
  *(ushort4*)(tbf + dst) = ut;
}

// ---------------------------------------------------------------------------
// Pair kernel v3: one block per (grp, it, b); 3 heads per block, 4 blocks/CU.
// MFMA bf16 scores for s and t, diff^2, per-head t-softmax (no max pass),
// accumulate att over the group's heads into LDS, write loc partial.
// ---------------------------------------------------------------------------
#define PITCH_L 516

__global__ __launch_bounds__(256, 4) void pair3_kernel(
    const unsigned short* __restrict__ sbf, const unsigned short* __restrict__ tbf,
    const float* __restrict__ mask, float* __restrict__ loc_part,
    float* __restrict__ g_score, double* __restrict__ acc) {
  const int b = blockIdx.x & 7;              // XCD-pinned batch
  const int it = (blockIdx.x >> 3) & 31;
  const int grp = blockIdx.x >> 8;           // 0..3
  const int i0 = it * 16;
  const int tid = threadIdx.x;
  const int w = tid >> 6;                    // wave 0..3: cols [w*128, +128)
  const int lane = tid & 63;
  const int lr = lane & 15;
  const int lg = lane >> 4;

  __shared__ float loc_acc[16][PITCH_L];
  __shared__ float Mcol[Ln];
  __shared__ float Mrow[16];
  __shared__ float redsum[2][4][16];
  __shared__ float wred[4];

  for (int idx = tid; idx < 16 * PITCH_L; idx += 256)
    (&loc_acc[0][0])[idx] = 0.0f;
  for (int j = tid; j < Ln; j += 256) Mcol[j] = mask[b * Ln + j];
  if (tid < 16) Mrow[tid] = mask[b * Ln + i0 + tid];
  __syncthreads();

  const int j_base = w * 128;
  const f32x4 zero4 = {0.0f, 0.0f, 0.0f, 0.0f};
  float lpair = 0.0f;

  for (int hh = 0; hh < HPG; ++hh) {
    const int h = grp * HPG + hh;
    const size_t hb = (size_t)(b * NHn + h) * Ln;
    const unsigned short* pas = sbf + (hb + i0 + lr) * DHn + lg * 8;
    const unsigned short* pat = tbf + (hb + i0 + lr) * DHn + lg * 8;
    bf16x8 sa0 = *(const bf16x8*)(pas);
    bf16x8 sa1 = *(const bf16x8*)(pas + 32);
    bf16x8 ta0 = *(const bf16x8*)(pat);
    bf16x8 ta1 = *(const bf16x8*)(pat + 32);

    f32x4 sacc[8], tacc[8];
    #pragma unroll
    for (int ct = 0; ct < 8; ++ct) {
      const int j0 = j_base + ct * 16;
      const unsigned short* pbs = sbf + (hb + j0 + lr) * DHn + lg * 8;
      const unsigned short* pbt = tbf + (hb + j0 + lr) * DHn + lg * 8;
      bf16x8 sb0 = *(const bf16x8*)(pbs);
      bf16x8 sb1 = *(const bf16x8*)(pbs + 32);
      bf16x8 tb0 = *(const bf16x8*)(pbt);
      bf16x8 tb1 = *(const bf16x8*)(pbt + 32);
      f32x4 a0 = __builtin_amdgcn_mfma_f32_16x16x32_bf16(sa0, sb0, zero4, 0, 0, 0);
      sacc[ct]  = __builtin_amdgcn_mfma_f32_16x16x32_bf16(sa1, sb1, a0, 0, 0, 0);
      f32x4 a1 = __builtin_amdgcn_mfma_f32_16x16x32_bf16(ta0, tb0, zero4, 0, 0, 0);
      tacc[ct]  = __builtin_amdgcn_mfma_f32_16x16x32_bf16(ta1, tb1, a1, 0, 0, 0);
    }

    // epilogue: masked diff^2 -> lpair; tacc <- exp(masked t score), no max pass
    float rsum[4] = {0.0f, 0.0f, 0.0f, 0.0f};
    #pragma unroll
    for (int ct = 0; ct < 8; ++ct) {
      const int j = j_base + ct * 16 + lr;
      const float mj = Mcol[j];
      #pragma unroll
      for (int q = 0; q < 4; ++q) {
        const int r = lg * 4 + q;
        const float mm = Mrow[r] * mj;
        const float ss = sacc[ct][q] * 0.125f * mm;
        const float st = tacc[ct][q] * 0.125f * mm;
        const float d = ss - st;
        lpair += d * d;
        const float e = __expf(st + (1.0f - mm) * (-10000.0f));
        tacc[ct][q] = e;
        rsum[q] += e;
      }
    }
    #pragma unroll
    for (int o = 1; o < 16; o <<= 1) {
      #pragma unroll
      for (int q = 0; q < 4; ++q) rsum[q] += __shfl_xor(rsum[q], o, 64);
    }
    if (lr == 0) {
      #pragma unroll
      for (int q = 0; q < 4; ++q) redsum[hh & 1][w][lg * 4 + q] = rsum[q];
    }
    __syncthreads();
    float rscale[4];
    #pragma unroll
    for (int q = 0; q < 4; ++q) {
      const int r = lg * 4 + q;
      const float fs = redsum[hh & 1][0][r] + redsum[hh & 1][1][r] +
                       redsum[hh & 1][2][r] + redsum[hh & 1][3][r];
      rscale[q] = Mrow[r] / fmaxf(fs, 1e-30f);
    }
    #pragma unroll
    for (int ct = 0; ct < 8; ++ct) {
      const int j = j_base + ct * 16 + lr;
      const float mj = Mcol[j];
      #pragma unroll
      for (int q = 0; q < 4; ++q)
        loc_acc[lg * 4 + q][j] += tacc[ct][q] * rscale[q] * mj;
    }
  }
  __syncthreads();

  // write loc partial (non-atomic, this group's buffer)
  float* lp = loc_part + (size_t)grp * GSTRIDE;
  for (int idx = tid; idx < 16 * 128; idx += 256) {
    const int r = idx >> 7;
    const int c4 = (idx & 127) * 4;
    float4 v = *(const float4*)&loc_acc[r][c4];
    *(float4*)&lp[((size_t)(b * Ln + i0 + r)) * Ln + c4] = v;
  }
  // g_score partials
  {
    const int j0 = tid, j1 = tid + 256;
    float g0 = 0.0f, g1 = 0.0f;
    for (int r = 0; r < 16; ++r) {
      g0 += loc_acc[r][j0];
      g1 += loc_acc[r][j1];
    }
    atomicAdd(&g_score[b * Ln + j0], g0);
    atomicAdd(&g_score[b * Ln + j1], g1);
  }
  // pair-loss partial
  #pragma unroll
  for (int o = 1; o < 64; o <<= 1) lpair += __shfl_xor(lpair, o, 64);
  if (lane == 0) wred[w] = lpair;
  __syncthreads();
  if (tid == 0)
    atomicAdd(&acc[0], (double)((wred[0] + wred[1]) + (wred[2] + wred[3])));
}

// ---------------------------------------------------------------------------
// Single-wave register top-k (iterative argmax, tie -> lowest index).
// ---------------------------------------------------------------------------
__global__ __launch_bounds__(64) void topk_g_kernel(
    const float* __restrict__ g_score, int* __restrict__ g_top) {
  const int b = blockIdx.x, lane = threadIdx.x;
  float v[8];
  #pragma unroll
  for (int q = 0; q < 8; ++q) v[q] = g_score[b * Ln + q * 64 + lane];
  for (int r = 0; r < K1n; ++r) {
    float bv = v[0]; int bq = 0;
    #pragma unroll
    for (int q = 1; q < 8; ++q) if (v[q] > bv) { bv = v[q]; bq = q; }
    int bj = bq * 64 + lane;
    #pragma unroll
    for (int o = 1; o < 64; o <<= 1) {
      float ov = __shfl_xor(bv, o, 64);
      int oj = __shfl_xor(bj, o, 64);
      if (ov > bv || (ov == bv && oj < bj)) { bv = ov; bj = oj; }
    }
    if (lane == 0) g_top[b * K1n + r] = bj;
    const int wq = bj >> 6, wl = bj & 63;
    #pragma unroll
    for (int q = 0; q < 8; ++q)
      if (q == wq && lane == wl) v[q] = -3.0e38f;
  }
}

__global__ __launch_bounds__(64) void topk_l_kernel(
    const float* __restrict__ loc_part, const int* __restrict__ g_top,
    int* __restrict__ l_top) {
  const int blk = blockIdx.x, lane = threadIdx.x;
  const int b = blk / K1n, i1 = blk % K1n;
  const int g = g_top[b * K1n + i1];
  const float* r0 = loc_part + ((size_t)(b * Ln + g)) * Ln;
  float v[8];
  #pragma unroll
  for (int q = 0; q < 8; ++q) {
    const int j = q * 64 + lane;
    float s = r0[j] + r0[j + GSTRIDE] + r0[j + 2 * GSTRIDE] + r0[j + 3 * GSTRIDE];
    v[q] = (j == g) ? 0.0f : s;    // (1 - eye) diagonal zero
  }
  for (int r = 0; r < K2n; ++r) {
    float bv = v[0]; int bq = 0;
    #pragma unroll
    for (int q = 1; q < 8; ++q) if (v[q] > bv) { bv = v[q]; bq = q; }
    int bj = bq * 64 + lane;
    #pragma unroll
    for (int o = 1; o < 64; o <<= 1) {
      float ov = __shfl_xor(bv, o, 64);
      int oj = __shfl_xor(bj, o, 64);
      if (ov > bv || (ov == bv && oj < bj)) { bv = ov; bj = oj; }
    }
    if (lane == 0) l_top[(b * K1n + i1) * K2n + r] = bj;
    const int wq = bj >> 6, wl = bj & 63;
    #pragma unroll
    for (int q = 0; q < 8; ++q)
      if (q == wq && lane == wl) v[q] = -3.0e38f;
  }
}

// ---------------------------------------------------------------------------
// Triplet loss. One block per (b, i1). fp32 throughout.
// ---------------------------------------------------------------------------
__global__ __launch_bounds__(256, 1) void triplet_kernel(
    const float* __restrict__ s_rep, const float* __restrict__ t_rep,
    const float* __restrict__ mask, const int* __restrict__ g_top,
    const int* __restrict__ l_top, double* __restrict__ acc) {
  int blk = blockIdx.x, tid = threadIdx.x;
  int b = blk / K1n, i1 = blk % K1n;
  int wid = tid >> 6, lane = tid & 63;
  __shared__ float NS[K2n][Dn];
  __shared__ float NT[K2n][Dn];
  __shared__ int lidx[K2n];
  __shared__ float fl2[K2n];
  __shared__ float sred[4], cred[4];

  int g = g_top[b * K1n + i1];
  if (tid < K2n) {
    int li = l_top[(b * K1n + i1) * K2n + tid];
    lidx[tid] = li;
    fl2[tid] = (mask[b * Ln + g] + mask[b * Ln + li] == 2.0f) ? 1.0f : 0.0f;
  }
  __syncthreads();

  const float* pgs = s_rep + ((size_t)(b * Ln + g)) * Dn;
  const float* pgt = t_rep + ((size_t)(b * Ln + g)) * Dn;
  for (int j = wid; j < K2n; j += 4) {
    const float* pls = s_rep + ((size_t)(b * Ln + lidx[j])) * Dn;
    const float* plt = t_rep + ((size_t)(b * Ln + lidx[j])) * Dn;
    float4 ds[3], dt[3];
    float ssq = 0.0f, tsq = 0.0f;
    #pragma unroll
    for (int q = 0; q < 3; ++q) {
      int c = lane * 4 + q * 256;
      float4 a = *(const float4*)&pgs[c];
      float4 x = *(const float4*)&pls[c];
      ds[q] = make_float4(a.x - x.x, a.y - x.y, a.z - x.z, a.w - x.w);
      ssq += ds[q].x * ds[q].x + ds[q].y * ds[q].y + ds[q].z * ds[q].z + ds[q].w * ds[q].w;
      float4 c2 = *(const float4*)&pgt[c];
      float4 y = *(const float4*)&plt[c];
      dt[q] = make_float4(c2.x - y.x, c2.y - y.y, c2.z - y.z, c2.w - y.w);
      tsq += dt[q].x * dt[q].x + dt[q].y * dt[q].y + dt[q].z * dt[q].z + dt[q].w * dt[q].w;
    }
    #pragma unroll
    for (int o = 1; o < 64; o <<= 1) {
      ssq += __shfl_xor(ssq, o, 64);
      tsq += __shfl_xor(tsq, o, 64);
    }
    float sinv = 1.0f / fmaxf(sqrtf(ssq), 1e-12f);
    float tinv = 1.0f / fmaxf(sqrtf(tsq), 1e-12f);
    #pragma unroll
    for (int q = 0; q < 3; ++q) {
      int c = lane * 4 + q * 256;
      *(float4*)&NS[j][c] = make_float4(ds[q].x * sinv, ds[q].y * sinv, ds[q].z * sinv, ds[q].w * sinv);
      *(float4*)&NT[j][c] = make_float4(dt[q].x * tinv, dt[q].y * tinv, dt[q].z * tinv, dt[q].w * tinv);
    }
  }
  __syncthreads();

  float psum = 0.0f, pcnt = 0.0f;
  for (int p = wid; p < (K2n * (K2n - 1)) / 2; p += 4) {
    int j = 0, base = 0;
    while (p >= base + (K2n - 1 - j)) { base += K2n - 1 - j; ++j; }
    int k = j + 1 + (p - base);
    float dots = 0.0f, dott = 0.0f;
    #pragma unroll
    for (int q = 0; q < 3; ++q) {
      int c = lane * 4 + q * 256;
      float4 xs = *(const float4*)&NS[j][c];
      float4 ys = *(const float4*)&NS[k][c];
      dots += xs.x * ys.x + xs.y * ys.y + xs.z * ys.z + xs.w * ys.w;
      float4 xt = *(const float4*)&NT[j][c];
      float4 yt = *(const float4*)&NT[k][c];
      dott += xt.x * yt.x + xt.y * yt.y + xt.z * yt.z + xt.w * yt.w;
    }
    #pragma unroll
    for (int o = 1; o < 64; o <<= 1) {
      dots += __shfl_xor(dots, o, 64);
      dott += __shfl_xor(dott, o, 64);
    }
    if (lane == 0) {
      float am = fl2[j] * fl2[k];
      bool smv = (am != 0.0f) && (dots != 0.0f);
      bool tmv = (am != 0.0f) && (dott != 0.0f);
      float sv = smv ? dots : 0.0f;
      float tv = tmv ? dott : 0.0f;
      float d = sv - tv;
      float ad = fabsf(d);
      float sl1 = (ad < 1.0f) ? 0.5f * d * d : (ad - 0.5f);
      psum += 2.0f * sl1;
      pcnt += smv ? 2.0f : 0.0f;
    }
  }
  if (lane == 0) { sred[wid] = psum; cred[wid] = pcnt; }
  __syncthreads();
  if (tid == 0) {
    atomicAdd(&acc[1], (double)(sred[0] + sred[1] + sred[2] + sred[3]));
    atomicAdd(&acc[2], (double)(cred[0] + cred[1] + cred[2] + cred[3]));
  }
}

// ---------------------------------------------------------------------------
__global__ void finalize_kernel(const float* __restrict__ mask,
                                const double* __restrict__ acc, float* __restrict__ out) {
  int tid = threadIdx.x;
  __shared__ float red[4];
  double sm = 0.0;
  for (int b = 0; b < Bn; ++b) {
    float p = 0.0f;
    for (int i = tid; i < Ln; i += 256) p += mask[b * Ln + i];
    #pragma unroll
    for (int o = 1; o < 64; o <<= 1) p += __shfl_xor(p, o, 64);
    __syncthreads();
    if ((tid & 63) == 0) red[tid >> 6] = p;
    __syncthreads();
    if (tid == 0) {
      float rs = red[0] + red[1] + red[2] + red[3];
      sm += (double)rs * (double)rs;
    }
  }
  __syncthreads();
  if (tid == 0) {
    double lp = acc[0] / ((double)NHn * sm);
    double lt = acc[1] / acc[2];
    out[0] = (float)(lp + lt);
  }
}

// ---------------------------------------------------------------------------
extern "C" void kernel_launch(void* const* d_in, const int* in_sizes, int n_in,
                              void* d_out, int out_size, void* d_ws, size_t ws_size,
                              hipStream_t stream) {
  const float* s_rep = (const float*)d_in[0];
  const float* t_rep = (const float*)d_in[1];
  const float* mask  = (const float*)d_in[2];
  float* out = (float*)d_out;

  char* w = (char*)d_ws;
  double* acc      = (double*)(w + WS_ACC);
  float* g_score   = (float*)(w + WS_GSCORE);
  float* loc_part  = (float*)(w + WS_LOC);
  int* g_top       = (int*)(w + WS_GTOP);
  int* l_top       = (int*)(w + WS_LTOP);
  unsigned short* sbf = (unsigned short*)(w + WS_SBF);
  unsigned short* tbf = (unsigned short*)(w + WS_TBF);

  hipMemsetAsync(d_ws, 0, WS_ZERO_BYTES, stream);

  prep_bf16_kernel<<<Bn * Ln * Dn / 4 / 256, 256, 0, stream>>>(s_rep, t_rep, sbf, tbf);
  pair3_kernel<<<NGRP * Bn * (Ln / 16), 256, 0, stream>>>(sbf, tbf, mask, loc_part, g_score, acc);
  topk_g_kernel<<<Bn, 64, 0, stream>>>(g_score, g_top);
  topk_l_kernel<<<Bn * K1n, 64, 0, stream>>>(loc_part, g_top, l_top);
  triplet_kernel<<<Bn * K1n, 256, 0, stream>>>(s_rep, t_rep, mask, g_top, l_top, acc);
  finalize_kernel<<<1, 256, 0, stream>>>(mask, acc, out);
}